// Round 2
// baseline (835.209 us; speedup 1.0000x reference)
//
#include <hip/hip_runtime.h>

typedef unsigned short u16;
typedef unsigned int u32;
typedef __bf16 bf16x8 __attribute__((ext_vector_type(8)));
typedef float f32x4 __attribute__((ext_vector_type(4)));
typedef u16 u16x4 __attribute__((ext_vector_type(4)));
typedef u16 u16x8 __attribute__((ext_vector_type(8)));

#define C_DIM 512
#define N_TOK 4096
#define HEADS 8
#define K3 1536

__device__ __forceinline__ u16 f2bf(float f) {
  u32 u = __builtin_bit_cast(u32, f);
  u += 0x7FFFu + ((u >> 16) & 1u);
  return (u16)(u >> 16);
}
__device__ __forceinline__ float bf2f(u16 b) {
  u32 u = ((u32)b) << 16;
  return __builtin_bit_cast(float, u);
}

// ---------- preps (unchanged from round 1) ----------

// w_qkv [1536][512] f32 -> A1 [1536][1536] bf16 cols = [hi | hi | lo]
__global__ void prep_w_kernel(const float* __restrict__ w, u16* __restrict__ A1) {
  int i = blockIdx.x * 256 + threadIdx.x;
  if (i >= 1536 * 512) return;
  int m = i >> 9, c = i & 511;
  float v = w[i];
  u16 hi = f2bf(v);
  u16 lo = f2bf(v - bf2f(hi));
  u16* row = A1 + (size_t)m * K3;
  row[c] = hi; row[512 + c] = hi; row[1024 + c] = lo;
}

__global__ void prep_wout_kernel(const float* __restrict__ w, u16* __restrict__ A2) {
  int i = blockIdx.x * 256 + threadIdx.x;
  if (i >= 512 * 512) return;
  A2[i] = f2bf(w[i]);
}

// x [512][4096] f32 -> B1 [4096][1536] bf16 cols = [xhi | xlo | xhi]
__global__ __launch_bounds__(256) void prep_x_kernel(const float* __restrict__ x, u16* __restrict__ B1) {
  __shared__ float lds[64][65];
  int n0 = blockIdx.x * 64, c0 = blockIdx.y * 64;
  int tid = threadIdx.x;
#pragma unroll
  for (int i = 0; i < 4; i++) {
    int idx = tid + i * 256;
    int r = idx >> 4, s = idx & 15;
    const float4 v = *(const float4*)(x + (size_t)(c0 + r) * N_TOK + n0 + s * 4);
    lds[r][s * 4 + 0] = v.x; lds[r][s * 4 + 1] = v.y;
    lds[r][s * 4 + 2] = v.z; lds[r][s * 4 + 3] = v.w;
  }
  __syncthreads();
  int n = tid >> 2, cs = tid & 3;
  u16x8 hv[2], lv[2];
#pragma unroll
  for (int half = 0; half < 2; half++) {
#pragma unroll
    for (int j = 0; j < 8; j++) {
      float v = lds[cs * 16 + half * 8 + j][n];
      u16 hi = f2bf(v);
      hv[half][j] = hi;
      lv[half][j] = f2bf(v - bf2f(hi));
    }
  }
  u16* row = B1 + (size_t)(n0 + n) * K3 + c0 + cs * 16;
  *(u16x8*)(row) = hv[0];
  *(u16x8*)(row + 8) = hv[1];
  *(u16x8*)(row + 512) = lv[0];
  *(u16x8*)(row + 520) = lv[1];
  *(u16x8*)(row + 1024) = hv[0];
  *(u16x8*)(row + 1032) = hv[1];
}

// ---------- NT GEMM (unchanged from round 1) ----------
__global__ __launch_bounds__(256) void gemm_nt_kernel(
    const u16* __restrict__ A, const u16* __restrict__ B, float* __restrict__ C,
    int M, int N, int K) {
  __shared__ char lds[128 * 64 * 2 * 2];
  char* ldsA = lds;
  char* ldsB = lds + 128 * 64 * 2;
  int n0 = blockIdx.x * 128, m0 = blockIdx.y * 128;
  int tid = threadIdx.x, lane = tid & 63, wid = tid >> 6;
  int wr = wid >> 1, wc = wid & 1;
  f32x4 acc[4][4] = {};
  for (int k0 = 0; k0 < K; k0 += 64) {
    __syncthreads();
#pragma unroll
    for (int i = 0; i < 4; i++) {
      int idx = tid + i * 256;
      int row = idx >> 3, cb = idx & 7;
      uint4 va = *(const uint4*)(A + (size_t)(m0 + row) * K + k0 + cb * 8);
      *(uint4*)(ldsA + row * 128 + ((cb * 16) ^ ((row & 7) << 4))) = va;
      uint4 vb = *(const uint4*)(B + (size_t)(n0 + row) * K + k0 + cb * 8);
      *(uint4*)(ldsB + row * 128 + ((cb * 16) ^ ((row & 7) << 4))) = vb;
    }
    __syncthreads();
#pragma unroll
    for (int kk = 0; kk < 2; kk++) {
      bf16x8 af[4], bfr[4];
#pragma unroll
      for (int mt = 0; mt < 4; mt++) {
        int row = wr * 64 + mt * 16 + (lane & 15);
        int kb = kk * 64 + ((lane >> 4) << 4);
        af[mt] = *(const bf16x8*)(ldsA + row * 128 + (kb ^ ((row & 7) << 4)));
      }
#pragma unroll
      for (int nt = 0; nt < 4; nt++) {
        int row = wc * 64 + nt * 16 + (lane & 15);
        int kb = kk * 64 + ((lane >> 4) << 4);
        bfr[nt] = *(const bf16x8*)(ldsB + row * 128 + (kb ^ ((row & 7) << 4)));
      }
#pragma unroll
      for (int mt = 0; mt < 4; mt++)
#pragma unroll
        for (int nt = 0; nt < 4; nt++)
          acc[mt][nt] = __builtin_amdgcn_mfma_f32_16x16x32_bf16(af[mt], bfr[nt], acc[mt][nt], 0, 0, 0);
    }
  }
#pragma unroll
  for (int mt = 0; mt < 4; mt++)
#pragma unroll
    for (int nt = 0; nt < 4; nt++) {
      int row = m0 + wr * 64 + mt * 16 + ((lane >> 4) << 2);
      int col = n0 + wc * 64 + nt * 16 + (lane & 15);
#pragma unroll
      for (int r = 0; r < 4; r++)
        C[(size_t)(row + r) * N + col] = acc[mt][nt][r];
    }
}

// ---------- NEW: fp32 per-head Q/K/V extraction ----------
// qkv [4096][1536] f32 -> Qf/Kf/Vf [8][4096][64] f32
__global__ void prep_qkv_f32(const float* __restrict__ qkv, float* __restrict__ Qf,
                             float* __restrict__ Kf, float* __restrict__ Vf) {
  int i = blockIdx.x * 256 + threadIdx.x;  // 8*4096*16 float4 units = 524288 -> grid 2048
  int d4 = i & 15;
  int n = (i >> 4) & 4095;
  int h = i >> 16;
  const f32x4* src = (const f32x4*)(qkv + (size_t)n * K3);
  f32x4 q = src[h * 16 + d4];
  f32x4 k = src[128 + h * 16 + d4];
  f32x4 v = src[256 + h * 16 + d4];
  size_t dst = ((size_t)h * N_TOK + n) * 16 + d4;
  ((f32x4*)Qf)[dst] = q;
  ((f32x4*)Kf)[dst] = k;
  ((f32x4*)Vf)[dst] = v;
}

// ---------- NEW: pure-fp32 VALU flash attention ----------
// Block = (64 q-rows, head). 256 threads: qg = tid>>4 owns q rows qg*4..+3,
// slot = tid&15 owns kv cols slot*4..+3 (QK) / dv cols slot*4..+3 (PV).
#define SQK 68  // f32 row stride for QsT/KsT/Vs
#define SP 72   // u16 row stride for Ps16
__global__ __launch_bounds__(256, 2) void attn_valu_kernel(
    const float* __restrict__ Qf, const float* __restrict__ Kf,
    const float* __restrict__ Vf, u16* __restrict__ Obuf) {
  __shared__ float QsT[64][SQK];  // [d][q]
  __shared__ float KsT[64][SQK];  // [d][kv]
  __shared__ float Vs[64][SQK];   // [kv][d]
  __shared__ u16 Ps16[64][SP];    // [q][kv] bf16
  int q0 = blockIdx.x * 64, h = blockIdx.y;
  int tid = threadIdx.x;
  int qg = tid >> 4, slot = tid & 15;

  // stage Q transposed (once)
  {
    int r = tid >> 2, ds = (tid & 3) * 16;
    const f32x4* s4 = (const f32x4*)(Qf + ((size_t)h * N_TOK + q0 + r) * 64 + ds);
#pragma unroll
    for (int c = 0; c < 4; c++) {
      f32x4 a = s4[c];
#pragma unroll
      for (int j = 0; j < 4; j++) QsT[ds + c * 4 + j][r] = a[j];
    }
  }

  float O[4][4] = {};
  float mr[4], lr[4];
#pragma unroll
  for (int r = 0; r < 4; r++) { mr[r] = -INFINITY; lr[r] = 0.f; }

  for (int kv0 = 0; kv0 < N_TOK; kv0 += 64) {
    __syncthreads();  // prior-iter LDS reads done (also covers Q-stage on iter 0)
    {
      int r = tid >> 2, ds = (tid & 3) * 16;
      const f32x4* ks = (const f32x4*)(Kf + ((size_t)h * N_TOK + kv0 + r) * 64 + ds);
#pragma unroll
      for (int c = 0; c < 4; c++) {
        f32x4 a = ks[c];
#pragma unroll
        for (int j = 0; j < 4; j++) KsT[ds + c * 4 + j][r] = a[j];
      }
      const f32x4* vs = (const f32x4*)(Vf + ((size_t)h * N_TOK + kv0 + r) * 64 + ds);
#pragma unroll
      for (int c = 0; c < 4; c++) *(f32x4*)(&Vs[r][ds + c * 4]) = vs[c];
    }
    __syncthreads();  // panels ready

    // S[rr][jj] = 8 * sum_d Q[q0+qg*4+rr][d] * K[kv0+slot*4+jj][d]
    float S[4][4] = {};
#pragma unroll
    for (int d = 0; d < 64; d++) {
      f32x4 q4 = *(const f32x4*)(&QsT[d][qg * 4]);
      f32x4 k4 = *(const f32x4*)(&KsT[d][slot * 4]);
#pragma unroll
      for (int rr = 0; rr < 4; rr++)
#pragma unroll
        for (int jj = 0; jj < 4; jj++) S[rr][jj] += q4[rr] * k4[jj];
    }

    // online softmax per q-row (16 slot-lanes hold the 64 kv cols)
#pragma unroll
    for (int rr = 0; rr < 4; rr++) {
      float m = -INFINITY;
#pragma unroll
      for (int jj = 0; jj < 4; jj++) { S[rr][jj] *= 8.0f; m = fmaxf(m, S[rr][jj]); }
#pragma unroll
      for (int d = 1; d < 16; d <<= 1) m = fmaxf(m, __shfl_xor(m, d));
      float mnew = fmaxf(mr[rr], m);
      float alpha = __expf(mr[rr] - mnew);
      mr[rr] = mnew;
      float ps = 0.f;
      float p[4];
#pragma unroll
      for (int jj = 0; jj < 4; jj++) { p[jj] = __expf(S[rr][jj] - mnew); ps += p[jj]; }
#pragma unroll
      for (int d = 1; d < 16; d <<= 1) ps += __shfl_xor(ps, d);
      lr[rr] = lr[rr] * alpha + ps;
#pragma unroll
      for (int u = 0; u < 4; u++) O[rr][u] *= alpha;
      // store P row-slice as bf16 pairs
      u32 w0 = (u32)f2bf(p[0]) | ((u32)f2bf(p[1]) << 16);
      u32 w1 = (u32)f2bf(p[2]) | ((u32)f2bf(p[3]) << 16);
      *(u32*)(&Ps16[qg * 4 + rr][slot * 4]) = w0;
      *(u32*)(&Ps16[qg * 4 + rr][slot * 4 + 2]) = w1;
    }
    __syncthreads();  // P visible across the row's 16 slot-threads

    // O[rr][u] += sum_kv P[q][kv] * V[kv][slot*4+u]
#pragma unroll
    for (int kvc = 0; kvc < 16; kvc++) {
      float p4[4][4];
#pragma unroll
      for (int rr = 0; rr < 4; rr++) {
        u16x4 pr = *(const u16x4*)(&Ps16[qg * 4 + rr][kvc * 4]);
#pragma unroll
        for (int jj = 0; jj < 4; jj++) p4[rr][jj] = bf2f(pr[jj]);
      }
      f32x4 v4[4];
#pragma unroll
      for (int jj = 0; jj < 4; jj++) v4[jj] = *(const f32x4*)(&Vs[kvc * 4 + jj][slot * 4]);
#pragma unroll
      for (int rr = 0; rr < 4; rr++)
#pragma unroll
        for (int jj = 0; jj < 4; jj++)
#pragma unroll
          for (int u = 0; u < 4; u++) O[rr][u] += p4[rr][jj] * v4[jj][u];
    }
  }

  // epilogue: normalize, bf16, store token-major [4096][512]
#pragma unroll
  for (int rr = 0; rr < 4; rr++) {
    int tok = q0 + qg * 4 + rr;
    u16* dst = Obuf + (size_t)tok * C_DIM + h * 64 + slot * 4;
    float inv = 1.0f / lr[rr];
    u16x4 outv;
#pragma unroll
    for (int u = 0; u < 4; u++) outv[u] = f2bf(O[rr][u] * inv);
    *(u16x4*)dst = outv;
  }
}

extern "C" void kernel_launch(void* const* d_in, const int* in_sizes, int n_in,
                              void* d_out, int out_size, void* d_ws, size_t ws_size,
                              hipStream_t stream) {
  const float* x = (const float*)d_in[0];      // [512][4096]
  const float* w_qkv = (const float*)d_in[1];  // [1536][512]
  const float* w_out = (const float*)d_in[2];  // [512][512]
  float* out = (float*)d_out;                  // [512][4096]
  char* ws = (char*)d_ws;
  size_t off = 0;
  u16* B1 = (u16*)(ws + off);    off += (size_t)N_TOK * K3 * 2;
  u16* A1 = (u16*)(ws + off);    off += (size_t)K3 * K3 * 2;
  u16* A2 = (u16*)(ws + off);    off += (size_t)512 * 512 * 2;
  float* qkv = (float*)(ws + off); off += (size_t)N_TOK * K3 * 4;
  float* Qf = (float*)(ws + off); off += (size_t)HEADS * N_TOK * 64 * 4;
  float* Kf = (float*)(ws + off); off += (size_t)HEADS * N_TOK * 64 * 4;
  float* Vf = (float*)(ws + off); off += (size_t)HEADS * N_TOK * 64 * 4;
  u16* Obuf = (u16*)(ws + off);  off += (size_t)N_TOK * C_DIM * 2;

  prep_w_kernel<<<(1536 * 512 + 255) / 256, 256, 0, stream>>>(w_qkv, A1);
  prep_wout_kernel<<<(512 * 512 + 255) / 256, 256, 0, stream>>>(w_out, A2);
  prep_x_kernel<<<dim3(64, 8), 256, 0, stream>>>(x, B1);
  gemm_nt_kernel<<<dim3(K3 / 128, N_TOK / 128), 256, 0, stream>>>(B1, A1, qkv, N_TOK, K3, K3);
  prep_qkv_f32<<<(HEADS * N_TOK * 16) / 256, 256, 0, stream>>>(qkv, Qf, Kf, Vf);
  attn_valu_kernel<<<dim3(N_TOK / 64, HEADS), 256, 0, stream>>>(Qf, Kf, Vf, Obuf);
  gemm_nt_kernel<<<dim3(N_TOK / 128, 512 / 128), 256, 0, stream>>>(A2, Obuf, out, 512, N_TOK, 512);
}

// Round 4
// 304.445 us; speedup vs baseline: 2.7434x; 2.7434x over previous
//
#include <hip/hip_runtime.h>

typedef unsigned short u16;
typedef unsigned int u32;
typedef __bf16 bf16x8 __attribute__((ext_vector_type(8)));
typedef float f32x4 __attribute__((ext_vector_type(4)));
typedef u16 u16x8 __attribute__((ext_vector_type(8)));

#define C_DIM 512
#define N_TOK 4096
#define HEADS 8
#define K3 1536

__device__ __forceinline__ u16 f2bf(float f) {
  u32 u = __builtin_bit_cast(u32, f);
  u += 0x7FFFu + ((u >> 16) & 1u);
  return (u16)(u >> 16);
}
__device__ __forceinline__ float bf2f(u16 b) {
  u32 u = ((u32)b) << 16;
  return __builtin_bit_cast(float, u);
}

// w_qkv [1536][512] f32 -> A1 [1536][1536] bf16 cols = [hi | hi | lo]
__global__ void prep_w_kernel(const float* __restrict__ w, u16* __restrict__ A1) {
  int i = blockIdx.x * 256 + threadIdx.x;
  if (i >= 1536 * 512) return;
  int m = i >> 9, c = i & 511;
  float v = w[i];
  u16 hi = f2bf(v);
  u16 lo = f2bf(v - bf2f(hi));
  u16* row = A1 + (size_t)m * K3;
  row[c] = hi; row[512 + c] = hi; row[1024 + c] = lo;
}

// w_out [512][512] f32 -> bf16
__global__ void prep_wout_kernel(const float* __restrict__ w, u16* __restrict__ A2) {
  int i = blockIdx.x * 256 + threadIdx.x;
  if (i >= 512 * 512) return;
  A2[i] = f2bf(w[i]);
}

// x [512][4096] f32 -> B1 [4096][1536] bf16 cols = [xhi | xlo | xhi] (transpose via LDS)
__global__ __launch_bounds__(256) void prep_x_kernel(const float* __restrict__ x, u16* __restrict__ B1) {
  __shared__ float lds[64][65];
  int n0 = blockIdx.x * 64, c0 = blockIdx.y * 64;
  int tid = threadIdx.x;
#pragma unroll
  for (int i = 0; i < 4; i++) {
    int idx = tid + i * 256;
    int r = idx >> 4, s = idx & 15;
    const float4 v = *(const float4*)(x + (size_t)(c0 + r) * N_TOK + n0 + s * 4);
    lds[r][s * 4 + 0] = v.x; lds[r][s * 4 + 1] = v.y;
    lds[r][s * 4 + 2] = v.z; lds[r][s * 4 + 3] = v.w;
  }
  __syncthreads();
  int n = tid >> 2, cs = tid & 3;
  u16x8 hv[2], lv[2];
#pragma unroll
  for (int half = 0; half < 2; half++) {
#pragma unroll
    for (int j = 0; j < 8; j++) {
      float v = lds[cs * 16 + half * 8 + j][n];
      u16 hi = f2bf(v);
      hv[half][j] = hi;
      lv[half][j] = f2bf(v - bf2f(hi));
    }
  }
  u16* row = B1 + (size_t)(n0 + n) * K3 + c0 + cs * 16;
  *(u16x8*)(row) = hv[0];
  *(u16x8*)(row + 8) = hv[1];
  *(u16x8*)(row + 512) = lv[0];
  *(u16x8*)(row + 520) = lv[1];
  *(u16x8*)(row + 1024) = hv[0];
  *(u16x8*)(row + 1032) = hv[1];
}

// NT GEMM: C[m][n] = sum_k A[m][k]*B[n][k]; 128x128 tile, BK=64, 4 waves, swizzled LDS.
__global__ __launch_bounds__(256) void gemm_nt_kernel(
    const u16* __restrict__ A, const u16* __restrict__ B, float* __restrict__ C,
    int M, int N, int K) {
  __shared__ char lds[128 * 64 * 2 * 2];
  char* ldsA = lds;
  char* ldsB = lds + 128 * 64 * 2;
  int n0 = blockIdx.x * 128, m0 = blockIdx.y * 128;
  int tid = threadIdx.x, lane = tid & 63, wid = tid >> 6;
  int wr = wid >> 1, wc = wid & 1;
  f32x4 acc[4][4] = {};
  for (int k0 = 0; k0 < K; k0 += 64) {
    __syncthreads();
#pragma unroll
    for (int i = 0; i < 4; i++) {
      int idx = tid + i * 256;
      int row = idx >> 3, cb = idx & 7;
      uint4 va = *(const uint4*)(A + (size_t)(m0 + row) * K + k0 + cb * 8);
      *(uint4*)(ldsA + row * 128 + ((cb * 16) ^ ((row & 7) << 4))) = va;
      uint4 vb = *(const uint4*)(B + (size_t)(n0 + row) * K + k0 + cb * 8);
      *(uint4*)(ldsB + row * 128 + ((cb * 16) ^ ((row & 7) << 4))) = vb;
    }
    __syncthreads();
#pragma unroll
    for (int kk = 0; kk < 2; kk++) {
      bf16x8 af[4], bfr[4];
#pragma unroll
      for (int mt = 0; mt < 4; mt++) {
        int row = wr * 64 + mt * 16 + (lane & 15);
        int kb = kk * 64 + ((lane >> 4) << 4);
        af[mt] = *(const bf16x8*)(ldsA + row * 128 + (kb ^ ((row & 7) << 4)));
      }
#pragma unroll
      for (int nt = 0; nt < 4; nt++) {
        int row = wc * 64 + nt * 16 + (lane & 15);
        int kb = kk * 64 + ((lane >> 4) << 4);
        bfr[nt] = *(const bf16x8*)(ldsB + row * 128 + (kb ^ ((row & 7) << 4)));
      }
#pragma unroll
      for (int mt = 0; mt < 4; mt++)
#pragma unroll
        for (int nt = 0; nt < 4; nt++)
          acc[mt][nt] = __builtin_amdgcn_mfma_f32_16x16x32_bf16(af[mt], bfr[nt], acc[mt][nt], 0, 0, 0);
    }
  }
#pragma unroll
  for (int mt = 0; mt < 4; mt++)
#pragma unroll
    for (int nt = 0; nt < 4; nt++) {
      int row = m0 + wr * 64 + mt * 16 + ((lane >> 4) << 2);
      int col = n0 + wc * 64 + nt * 16 + (lane & 15);
#pragma unroll
      for (int r = 0; r < 4; r++)
        C[(size_t)(row + r) * N + col] = acc[mt][nt][r];
    }
}

// qkv [4096][1536] f32 -> Qp/Kp [8][4096][192] bf16 (Q'=[hi|hi|lo], K'=[hi|lo|hi])
__global__ void prep_qk_kernel(const float* __restrict__ qkv, u16* __restrict__ Qp, u16* __restrict__ Kp) {
  int i = blockIdx.x * 256 + threadIdx.x;  // 8*4096*64 = 2097152 exact
  int dh = i & 63;
  int n = (i >> 6) & 4095;
  int h = i >> 18;
  float q = qkv[(size_t)n * K3 + h * 64 + dh];
  float k = qkv[(size_t)n * K3 + 512 + h * 64 + dh];
  u16 qhi = f2bf(q); u16 qlo = f2bf(q - bf2f(qhi));
  u16 khi = f2bf(k); u16 klo = f2bf(k - bf2f(khi));
  u16* qr = Qp + ((size_t)h * N_TOK + n) * 192;
  u16* kr = Kp + ((size_t)h * N_TOK + n) * 192;
  qr[dh] = qhi; qr[64 + dh] = qhi; qr[128 + dh] = qlo;
  kr[dh] = khi; kr[64 + dh] = klo; kr[128 + dh] = khi;
}

// qkv V-part [4096][h*64] -> Vt [8][64][4096] bf16 (V^T per head, via LDS transpose)
__global__ __launch_bounds__(256) void prep_v_kernel(const float* __restrict__ qkv, u16* __restrict__ Vt) {
  __shared__ float lds[64][65];
  int n0 = blockIdx.x * 64, h = blockIdx.y;
  int tid = threadIdx.x;
#pragma unroll
  for (int i = 0; i < 4; i++) {
    int idx = tid + i * 256;
    int r = idx >> 4, s = idx & 15;
    const float4 v = *(const float4*)(qkv + (size_t)(n0 + r) * K3 + 1024 + h * 64 + s * 4);
    lds[r][s * 4 + 0] = v.x; lds[r][s * 4 + 1] = v.y;
    lds[r][s * 4 + 2] = v.z; lds[r][s * 4 + 3] = v.w;
  }
  __syncthreads();
  int dh = tid >> 2, ns = tid & 3;
  u16x8 pv[2];
#pragma unroll
  for (int half = 0; half < 2; half++)
#pragma unroll
    for (int j = 0; j < 8; j++)
      pv[half][j] = f2bf(lds[ns * 16 + half * 8 + j][dh]);
  u16* dst = Vt + ((size_t)h * 64 + dh) * N_TOK + n0 + ns * 16;
  *(u16x8*)(dst) = pv[0];
  *(u16x8*)(dst + 8) = pv[1];
}

// Flash attention: block = (64 q-rows, head), 4 waves x 16 q-rows, kv tiles of 64.
__global__ __launch_bounds__(256) void attn_kernel(
    const u16* __restrict__ Qp, const u16* __restrict__ Kp,
    const u16* __restrict__ Vt, u16* __restrict__ Obuf) {
  __shared__ char lds[24 * 1024 + 8 * 1024 + 8 * 1024];
  char* ldsK = lds;             // [64 tok][192] bf16, swizzled, row 384B
  char* ldsV = lds + 24 * 1024; // [64 dh][64 kv] bf16, swizzled, row 128B
  char* ldsP = lds + 32 * 1024; // per-wave [16 q][64 kv] bf16 scratch
  int q0 = blockIdx.x * 64, h = blockIdx.y;
  int tid = threadIdx.x, lane = tid & 63, wid = tid >> 6;
  char* myP = ldsP + wid * 2048;
  bf16x8 qf[6];
  {
    const u16* qrow = Qp + ((size_t)h * N_TOK + q0 + wid * 16 + (lane & 15)) * 192 + ((lane >> 4) * 8);
#pragma unroll
    for (int c = 0; c < 6; c++) qf[c] = *(const bf16x8*)(qrow + c * 32);
  }
  f32x4 o[4] = {};
  float mrow[4], lrow[4];
#pragma unroll
  for (int r = 0; r < 4; r++) { mrow[r] = -INFINITY; lrow[r] = 0.f; }

  for (int kv0 = 0; kv0 < N_TOK; kv0 += 64) {
    __syncthreads();  // prior iter's LDS reads done
#pragma unroll
    for (int i = 0; i < 6; i++) {
      int idx = tid + i * 256;
      int row = idx / 24, cb = idx % 24;
      uint4 v = *(const uint4*)(Kp + ((size_t)h * N_TOK + kv0 + row) * 192 + cb * 8);
      *(uint4*)(ldsK + row * 384 + ((cb * 16) ^ ((row & 7) << 4))) = v;
    }
#pragma unroll
    for (int i = 0; i < 2; i++) {
      int idx = tid + i * 256;
      int row = idx >> 3, cb = idx & 7;
      uint4 v = *(const uint4*)(Vt + ((size_t)h * 64 + row) * N_TOK + kv0 + cb * 8);
      *(uint4*)(ldsV + row * 128 + ((cb * 16) ^ ((row & 7) << 4))) = v;
    }
    __syncthreads();  // panels ready
    // S = (Q . K^T) * 8, split-precision via K-dim 192
    f32x4 s[4];
#pragma unroll
    for (int nt = 0; nt < 4; nt++) {
      f32x4 acc = {};
      int row = nt * 16 + (lane & 15);
      const char* kbase = ldsK + row * 384;
      int swz = (row & 7) << 4;
#pragma unroll
      for (int c = 0; c < 6; c++) {
        int kb = c * 64 + ((lane >> 4) << 4);
        bf16x8 kf = *(const bf16x8*)(kbase + (kb ^ swz));
        acc = __builtin_amdgcn_mfma_f32_16x16x32_bf16(qf[c], kf, acc, 0, 0, 0);
      }
      s[nt] = acc * 8.0f;
    }
    // online softmax (rows spread: row=(lane>>4)*4+r, cols=lane&15 per nt)
    float pmax[4];
#pragma unroll
    for (int r = 0; r < 4; r++) {
      float m = fmaxf(fmaxf(s[0][r], s[1][r]), fmaxf(s[2][r], s[3][r]));
#pragma unroll
      for (int d = 1; d < 16; d <<= 1) m = fmaxf(m, __shfl_xor(m, d));
      pmax[r] = m;
    }
    float alpha[4];
#pragma unroll
    for (int r = 0; r < 4; r++) {
      float mnew = fmaxf(mrow[r], pmax[r]);
      alpha[r] = __expf(mrow[r] - mnew);
      mrow[r] = mnew;
    }
    float psum[4] = {0.f, 0.f, 0.f, 0.f};
#pragma unroll
    for (int nt = 0; nt < 4; nt++)
#pragma unroll
      for (int r = 0; r < 4; r++) {
        float p = __expf(s[nt][r] - mrow[r]);
        s[nt][r] = p;
        psum[r] += p;
      }
#pragma unroll
    for (int r = 0; r < 4; r++) {
      float t = psum[r];
#pragma unroll
      for (int d = 1; d < 16; d <<= 1) t += __shfl_xor(t, d);
      lrow[r] = lrow[r] * alpha[r] + t;
      o[0][r] *= alpha[r]; o[1][r] *= alpha[r]; o[2][r] *= alpha[r]; o[3][r] *= alpha[r];
    }
    // P -> per-wave LDS scratch (bf16), C-layout -> A-layout transpose
#pragma unroll
    for (int nt = 0; nt < 4; nt++)
#pragma unroll
      for (int r = 0; r < 4; r++) {
        int prow = ((lane >> 4) << 2) + r;
        int kvb = (nt * 16 + (lane & 15)) * 2;
        *(u16*)(myP + prow * 128 + (kvb ^ ((prow & 7) << 4))) = f2bf(s[nt][r]);
      }
    __syncthreads();  // P visible; V still valid
    // O += P . V
#pragma unroll
    for (int c = 0; c < 2; c++) {
      int prow = lane & 15;
      int kb = c * 64 + ((lane >> 4) << 4);
      bf16x8 pf = *(const bf16x8*)(myP + prow * 128 + (kb ^ ((prow & 7) << 4)));
#pragma unroll
      for (int nt = 0; nt < 4; nt++) {
        int vrow = nt * 16 + (lane & 15);
        bf16x8 vf = *(const bf16x8*)(ldsV + vrow * 128 + (kb ^ ((vrow & 7) << 4)));
        o[nt] = __builtin_amdgcn_mfma_f32_16x16x32_bf16(pf, vf, o[nt], 0, 0, 0);
      }
    }
  }
  // normalize + write O (bf16, token-major [4096][512]) via LDS transpose
#pragma unroll
  for (int nt = 0; nt < 4; nt++)
#pragma unroll
    for (int r = 0; r < 4; r++) {
      int row = ((lane >> 4) << 2) + r;
      int colb = (nt * 16 + (lane & 15)) * 2;
      float v = o[nt][r] / lrow[r];
      *(u16*)(myP + row * 128 + (colb ^ ((row & 7) << 4))) = f2bf(v);
    }
  __syncthreads();
  {
    // FIX (round 3 bug): each 128B row needs 8 x 16B chunks; 4 lanes/row must
    // each read TWO uint4s (s16 = seg, seg+4), not one — previously dv 32..63
    // of every head were never written.
    int row = lane >> 2, seg = lane & 3;
#pragma unroll
    for (int half = 0; half < 2; half++) {
      int s16 = seg + half * 4;
      uint4 v = *(const uint4*)(myP + row * 128 + ((s16 * 16) ^ ((row & 7) << 4)));
      *(uint4*)(Obuf + ((size_t)(q0 + wid * 16 + row)) * C_DIM + h * 64 + s16 * 8) = v;
    }
  }
}

extern "C" void kernel_launch(void* const* d_in, const int* in_sizes, int n_in,
                              void* d_out, int out_size, void* d_ws, size_t ws_size,
                              hipStream_t stream) {
  const float* x = (const float*)d_in[0];      // [512][4096]
  const float* w_qkv = (const float*)d_in[1];  // [1536][512]
  const float* w_out = (const float*)d_in[2];  // [512][512]
  float* out = (float*)d_out;                  // [512][4096]
  char* ws = (char*)d_ws;
  // Workspace layout with overlays (total 68,157,440 B <= proven-available).
  // B1/A1 are dead after gemm1: Obuf overlays B1, Vt overlays A1.
  size_t off = 0;
  size_t off_B1 = off;  off += (size_t)N_TOK * K3 * 2;       // 12,582,912
  size_t off_A1 = off;  off += (size_t)K3 * K3 * 2;          //  4,718,592
  size_t off_A2 = off;  off += (size_t)512 * 512 * 2;        //    524,288
  size_t off_qkv = off; off += (size_t)N_TOK * K3 * 4;       // 25,165,824
  size_t off_Qp = off;  off += (size_t)HEADS * N_TOK * 192 * 2; // 12,582,912
  size_t off_Kp = off;  off += (size_t)HEADS * N_TOK * 192 * 2; // 12,582,912
  u16* B1 = (u16*)(ws + off_B1);
  u16* A1 = (u16*)(ws + off_A1);
  u16* A2 = (u16*)(ws + off_A2);
  float* qkv = (float*)(ws + off_qkv);
  u16* Qp = (u16*)(ws + off_Qp);
  u16* Kp = (u16*)(ws + off_Kp);
  u16* Vt = (u16*)(ws + off_A1);    // overlay A1 (4,194,304 <= 4,718,592)
  u16* Obuf = (u16*)(ws + off_B1);  // overlay B1 (4,194,304 <= 12,582,912)

  prep_w_kernel<<<(1536 * 512 + 255) / 256, 256, 0, stream>>>(w_qkv, A1);
  prep_wout_kernel<<<(512 * 512 + 255) / 256, 256, 0, stream>>>(w_out, A2);
  prep_x_kernel<<<dim3(64, 8), 256, 0, stream>>>(x, B1);
  // qkv[token][channel] = sum_k B1[token][k] * A1[channel][k]
  gemm_nt_kernel<<<dim3(K3 / 128, N_TOK / 128), 256, 0, stream>>>(B1, A1, qkv, N_TOK, K3, K3);
  prep_qk_kernel<<<(HEADS * N_TOK * 64) / 256, 256, 0, stream>>>(qkv, Qp, Kp);
  prep_v_kernel<<<dim3(64, 8), 256, 0, stream>>>(qkv, Vt);
  attn_kernel<<<dim3(64, 8), 256, 0, stream>>>(Qp, Kp, Vt, Obuf);
  // out[channel][token] = sum_k w_out[channel][k] * Obuf[token][k]
  gemm_nt_kernel<<<dim3(N_TOK / 128, 512 / 128), 256, 0, stream>>>(A2, Obuf, out, 512, N_TOK, 512);
}